// Round 7
// baseline (620.390 us; speedup 1.0000x reference)
//
#include <hip/hip_runtime.h>
#include <hip/hip_fp16.h>

#define T_LEN   262144
#define NV      20
#define NE      30
#define NH      40
#define NG      160                    // 4*NH
#define CHUNK   512
#define WARM    64
#define SPC     (WARM + CHUNK)         // 576
#define NBLK    (T_LEN / CHUNK)        // 512
#define SS      32                     // steps per super-step
#define NSS     (SPC / SS)             // 18
#define WUSS    (WARM / SS)            // 2
#define NTHR    192

typedef _Float16 half2v __attribute__((ext_vector_type(2)));
typedef unsigned u32x4  __attribute__((ext_vector_type(4)));

__device__ __forceinline__ float sig_(float x) {
    x = fminf(fmaxf(x, -30.f), 30.f);
    return __fdividef(1.f, 1.f + __expf(-x));
}
__device__ __forceinline__ float tanh_(float x) {
    x = fminf(fmaxf(x, -15.f), 15.f);
    float e = __expf(2.f * x);
    return __fdividef(e - 1.f, e + 1.f);
}
// pack two f32 into one u32 holding an f16 pair
__device__ __forceinline__ unsigned pkf_(float a, float b) {
    unsigned lo = (unsigned)__half_as_ushort(__float2half(a));
    unsigned hi = (unsigned)__half_as_ushort(__float2half(b));
    return lo | (hi << 16);
}
// f16x2 dot with f32 accumulate (v_dot2_f32_f16)
__device__ __forceinline__ float dot2_(unsigned hp, unsigned wp, float c) {
#if __has_builtin(__builtin_amdgcn_fdot2)
    return __builtin_amdgcn_fdot2(__builtin_bit_cast(half2v, hp),
                                  __builtin_bit_cast(half2v, wp), c, false);
#else
    __half2 h = __builtin_bit_cast(__half2, hp);
    __half2 w = __builtin_bit_cast(__half2, wp);
    return fmaf(__half2float(h.x), __half2float(w.x),
           fmaf(__half2float(h.y), __half2float(w.y), c));
#endif
}

// Wave roles (192 thr = 3 waves):
//   wave 0/1: LSTM cell per direction — lane k owns unit k; the 80 packed-f16
//             weight words live in LDS ([dir][q][k] 16B chunks: 40 lanes map
//             5-per-4-bank-group uniformly -> 5cy/b128, zero conflict penalty).
//             h feedback via readlane of f16 bits. No large register sets ->
//             nothing for the allocator to spill.
//   wave 2:   logits — f16 h-ring (double-buffered, 1 barrier / 32 steps);
//             logit weights also in LDS.
extern "C" __global__ __attribute__((amdgpu_waves_per_eu(1, 2))) void
__launch_bounds__(NTHR)
bilstm_kernel(const int* __restrict__ tokens,
              const float* __restrict__ embed,
              const float* __restrict__ W_ih1, const float* __restrict__ W_hh1,
              const float* __restrict__ b_ih1, const float* __restrict__ b_hh1,
              const float* __restrict__ W_ih2, const float* __restrict__ W_hh2,
              const float* __restrict__ b_ih2, const float* __restrict__ b_hh2,
              const float* __restrict__ W_l1,  const float* __restrict__ b_l1,
              const float* __restrict__ W_l2,  const float* __restrict__ b_l2,
              float* __restrict__ out)
{
    __shared__ __align__(16) float  tab[2 * NV * NH * 4];       // x-pre lookup, f32
    __shared__ __align__(16) u32x4  Wlds[2][20][NH];            // cell weights, f16 pairs
    __shared__ __align__(16) u32x4  Wl_lds[2][5][NV];           // logit weights
    __shared__ __align__(16) unsigned short ring16[2][2][SS][64]; // f16 h ring
    __shared__ __align__(16) float  embS[NV * NE];
    __shared__ int tokS[2][SPC];

    const int tid  = threadIdx.x;
    const int wave = tid >> 6;
    const int lane = tid & 63;
    const int a    = blockIdx.x * CHUNK;

    // ---- stage embed + tokens ----
    for (int p = tid; p < NV * NE; p += NTHR) embS[p] = embed[p];
    for (int p = tid; p < SPC; p += NTHR) {
        int t = a - WARM + p;
        if (t >= 0) {
            tokS[0][p] = tokens[t];
            tokS[1][p] = tokens[T_LEN - 1 - t];
        }
    }
    __syncthreads();

    // ---- x-pre tables: tab[((d*NV+v)*NH+k)*4+g] = emb[v]·W_ih[g*NH+k] + b_ih+b_hh ----
    for (int p = tid; p < 2 * NV * NG; p += NTHR) {
        int g = p & 3, r = p >> 2;
        int k = r % NH, q = r / NH;
        int v = q % NV, dd = q / NV;
        const float* Wih = dd ? W_ih2 : W_ih1;
        const float* bi  = dd ? b_ih2 : b_ih1;
        const float* bh  = dd ? b_hh2 : b_hh1;
        int j = g * NH + k;
        float acc = bi[j] + bh[j];
        #pragma unroll
        for (int e = 0; e < NE; ++e) acc += embS[v * NE + e] * Wih[j * NE + e];
        tab[p] = acc;
    }

    // ---- stage cell weights into LDS: flat u32 p = ((dd*20+q)*40+k)*4+u ----
    // chunk q: gate g=q/5, pairs m=4*(q%5)+u ; row j=g*40+k ; pair (j,2m),(j,2m+1)
    {
        unsigned* WU = (unsigned*)Wlds;
        for (int p = tid; p < 6400; p += NTHR) {
            int dd = p / 3200, r = p % 3200;
            int u  = r & 3,    ch = r >> 2;
            int q  = ch / NH,  k  = ch % NH;
            int g  = q / 5,    m  = 4 * (q % 5) + u;
            const float* Whh = dd ? W_hh2 : W_hh1;
            int j = g * NH + k;
            WU[p] = pkf_(Whh[j * NH + 2 * m], Whh[j * NH + 2 * m + 1]);
        }
    }
    // ---- stage logit weights: flat u32 p = ((half*5+q)*20+v)*4+u ; m=4q+u ----
    {
        unsigned* WU = (unsigned*)Wl_lds;
        for (int p = tid; p < 800; p += NTHR) {
            int half = p / 400, r = p % 400;
            int u = r & 3, ch = r >> 2;
            int q = ch / NV, v = ch % NV;
            int m = 4 * q + u;
            const float* Wl = half ? W_l2 : W_l1;
            WU[p] = pkf_(Wl[v * NH + 2 * m], Wl[v * NH + 2 * m + 1]);
        }
    }

    // ---- per-wave setup ----
    const bool isCell = (wave < 2);
    const int  dir    = wave;
    const int  kk     = (lane < NH) ? lane : NH - 1;

    float lb = 0.f;
    if (isCell) {
        __builtin_amdgcn_s_setprio(1);   // cell waves are the critical path
    } else {
        int half = lane >> 5, v = lane & 31;
        int vv   = (v < NV) ? v : NV - 1;
        if (!half) lb = b_l1[vv] + b_l2[vv];
    }
    __syncthreads();   // tab + tokS + weights ready

    // ---- cell init + first x-pre prefetch ----
    const int cell_ss0 = (a < WARM) ? WUSS : 0;  // block 0 starts exactly at s=WARM
    int   hb = 0;                                 // f16 bits of own h
    float c  = 0.f;
    float x0 = 0.f, x1 = 0.f, x2 = 0.f, x3 = 0.f;
    if (isCell) {
        int tk = tokS[dir][cell_ss0 * SS];
        float4 xv = *(const float4*)&tab[((dir * NV + tk) * NH + kk) * 4];
        x0 = xv.x; x1 = xv.y; x2 = xv.z; x3 = xv.w;
    }

    // ---- main loop: NSS super-steps of SS steps + 1 logit flush ----
    #pragma unroll 1
    for (int ss = 0; ss <= NSS; ++ss) {
        if (isCell && ss >= cell_ss0 && ss < NSS) {
            const int sbase = ss * SS;
            #pragma unroll 1
            for (int sl = 0; sl < SS; ++sl) {
                const int s = sbase + sl;
                float ai = x0, af = x1, ag = x2, ao = x3;
                unsigned wofs = 0;
                asm volatile("" : "+v"(wofs));        // block LICM of weight reads
                const u32x4* wb = &Wlds[dir][0][kk] + wofs;
                #pragma unroll
                for (int m4 = 0; m4 < 5; ++m4) {
                    u32x4 vi = wb[(0 * 5 + m4) * NH];   // ds_read_b128, imm offsets
                    u32x4 vf = wb[(1 * 5 + m4) * NH];
                    u32x4 vg = wb[(2 * 5 + m4) * NH];
                    u32x4 vo = wb[(3 * 5 + m4) * NH];
                    #pragma unroll
                    for (int u = 0; u < 4; ++u) {
                        const int m = 4 * m4 + u;
                        unsigned lo = (unsigned)__builtin_amdgcn_readlane(hb, 2 * m);
                        unsigned hi = (unsigned)__builtin_amdgcn_readlane(hb, 2 * m + 1);
                        unsigned hp = lo | (hi << 16);
                        ai = dot2_(hp, vi[u], ai);
                        af = dot2_(hp, vf[u], af);
                        ag = dot2_(hp, vg[u], ag);
                        ao = dot2_(hp, vo[u], ao);
                    }
                }
                int sn = (s + 1 < SPC) ? s + 1 : SPC - 1;   // prefetch next x-pre
                int tk = tokS[dir][sn];
                float4 xv = *(const float4*)&tab[((dir * NV + tk) * NH + kk) * 4];
                x0 = xv.x; x1 = xv.y; x2 = xv.z; x3 = xv.w;
                float I = sig_(ai), F = sig_(af), G = tanh_(ag), O = sig_(ao);
                c = fmaf(F, c, I * G);
                float hh = O * tanh_(c);
                hb = (int)__half_as_ushort(__float2half(hh));
                ring16[ss & 1][dir][sl][lane] = (unsigned short)hb;
            }
        }
        if (!isCell && ss > WUSS && ss <= NSS) {
            const int b = ss - 1, par = b & 1;
            const int half = lane >> 5, v = lane & 31;
            const int vv = (v < NV) ? v : NV - 1;
            #pragma unroll 1
            for (int sl = 0; sl < SS; ++sl) {
                const u32x4* hr4 = (const u32x4*)ring16[par][half][sl]; // uniform addr
                float acc = 0.f;
                #pragma unroll
                for (int q = 0; q < 5; ++q) {
                    u32x4 hq = hr4[q];
                    u32x4 wv = Wl_lds[half][q][vv];
                    acc = dot2_(hq[0], wv[0], acc);
                    acc = dot2_(hq[1], wv[1], acc);
                    acc = dot2_(hq[2], wv[2], acc);
                    acc = dot2_(hq[3], wv[3], acc);
                }
                float oth = __shfl_xor(acc, 32, 64);
                if (half == 0 && v < NV) {
                    int trow = a + b * SS + sl - WARM;
                    out[(size_t)trow * NV + v] = acc + oth + lb;
                }
            }
        }
        __syncthreads();
    }
}

extern "C" void kernel_launch(void* const* d_in, const int* in_sizes, int n_in,
                              void* d_out, int out_size, void* d_ws, size_t ws_size,
                              hipStream_t stream)
{
    const int*   tokens = (const int*)  d_in[0];
    const float* embed  = (const float*)d_in[1];
    const float* W_ih1  = (const float*)d_in[2];
    const float* W_hh1  = (const float*)d_in[3];
    const float* b_ih1  = (const float*)d_in[4];
    const float* b_hh1  = (const float*)d_in[5];
    const float* W_ih2  = (const float*)d_in[6];
    const float* W_hh2  = (const float*)d_in[7];
    const float* b_ih2  = (const float*)d_in[8];
    const float* b_hh2  = (const float*)d_in[9];
    const float* W_l1   = (const float*)d_in[10];
    const float* b_l1   = (const float*)d_in[11];
    const float* W_l2   = (const float*)d_in[12];
    const float* b_l2   = (const float*)d_in[13];
    float* outp = (float*)d_out;

    hipLaunchKernelGGL(bilstm_kernel, dim3(NBLK), dim3(NTHR), 0, stream,
                       tokens, embed, W_ih1, W_hh1, b_ih1, b_hh1,
                       W_ih2, W_hh2, b_ih2, b_hh2, W_l1, b_l1, W_l2, b_l2, outp);
}

// Round 9
// 417.441 us; speedup vs baseline: 1.4862x; 1.4862x over previous
//
#include <hip/hip_runtime.h>
#include <hip/hip_fp16.h>

#define T_LEN   262144
#define NV      20
#define NE      30
#define NH      40
#define CHUNK   256
#define WARM    64
#define SPC     (WARM + CHUNK)         // 320
#define NBLK    (T_LEN / CHUNK)        // 1024
#define SS      32                     // steps per super-step
#define NSS     (SPC / SS)             // 10
#define WUSS    (WARM / SS)            // 2
#define NTHR    128

typedef _Float16 half2v __attribute__((ext_vector_type(2)));
typedef unsigned u32x2  __attribute__((ext_vector_type(2)));

__device__ __forceinline__ float sig_(float x) {
    x = fminf(fmaxf(x, -30.f), 30.f);
    return __fdividef(1.f, 1.f + __expf(-x));
}
__device__ __forceinline__ float tanh_(float x) {
    x = fminf(fmaxf(x, -15.f), 15.f);
    float e = __expf(2.f * x);
    return __fdividef(e - 1.f, e + 1.f);
}
__device__ __forceinline__ unsigned pkf_(float a, float b) {
    unsigned lo = (unsigned)__half_as_ushort(__float2half(a));
    unsigned hi = (unsigned)__half_as_ushort(__float2half(b));
    return lo | (hi << 16);
}
__device__ __forceinline__ float lo16f_(unsigned u) {
    return __half2float(__ushort_as_half((unsigned short)(u & 0xffffu)));
}
__device__ __forceinline__ float hi16f_(unsigned u) {
    return __half2float(__ushort_as_half((unsigned short)(u >> 16)));
}
__device__ __forceinline__ float dot2_(unsigned hp, unsigned wp, float c) {
#if __has_builtin(__builtin_amdgcn_fdot2)
    return __builtin_amdgcn_fdot2(__builtin_bit_cast(half2v, hp),
                                  __builtin_bit_cast(half2v, wp), c, false);
#else
    __half2 h = __builtin_bit_cast(__half2, hp);
    __half2 w = __builtin_bit_cast(__half2, wp);
    return fmaf(__half2float(h.x), __half2float(w.x),
           fmaf(__half2float(h.y), __half2float(w.y), c));
#endif
}

#define D20(V) unsigned V##0,V##1,V##2,V##3,V##4,V##5,V##6,V##7,V##8,V##9, \
    V##10,V##11,V##12,V##13,V##14,V##15,V##16,V##17,V##18,V##19
#define L20(V, P) do { const float* _q = (P); \
    V##0 =pkf_(_q[0],_q[1]);   V##1 =pkf_(_q[2],_q[3]);   V##2 =pkf_(_q[4],_q[5]); \
    V##3 =pkf_(_q[6],_q[7]);   V##4 =pkf_(_q[8],_q[9]);   V##5 =pkf_(_q[10],_q[11]); \
    V##6 =pkf_(_q[12],_q[13]); V##7 =pkf_(_q[14],_q[15]); V##8 =pkf_(_q[16],_q[17]); \
    V##9 =pkf_(_q[18],_q[19]); V##10=pkf_(_q[20],_q[21]); V##11=pkf_(_q[22],_q[23]); \
    V##12=pkf_(_q[24],_q[25]); V##13=pkf_(_q[26],_q[27]); V##14=pkf_(_q[28],_q[29]); \
    V##15=pkf_(_q[30],_q[31]); V##16=pkf_(_q[32],_q[33]); V##17=pkf_(_q[34],_q[35]); \
    V##18=pkf_(_q[36],_q[37]); V##19=pkf_(_q[38],_q[39]); } while(0)
#define Z20(V) do { V##0=V##1=V##2=V##3=V##4=V##5=V##6=V##7=V##8=V##9=0u; \
    V##10=V##11=V##12=V##13=V##14=V##15=V##16=V##17=V##18=V##19=0u; } while(0)
// KEEP *inside* the step loop: all 20 words must be live-in-VGPR every
// iteration -> spilling them costs 20 reloads/iter -> allocator keeps them.
#define K20(V) asm volatile("" : \
    "+v"(V##0),"+v"(V##1),"+v"(V##2),"+v"(V##3),"+v"(V##4), \
    "+v"(V##5),"+v"(V##6),"+v"(V##7),"+v"(V##8),"+v"(V##9), \
    "+v"(V##10),"+v"(V##11),"+v"(V##12),"+v"(V##13),"+v"(V##14), \
    "+v"(V##15),"+v"(V##16),"+v"(V##17),"+v"(V##18),"+v"(V##19))

// one h-pair broadcast (readlane of lanes 0..39) feeding 4 dot chains;
// logit lanes (40..59) ride the same instructions with w=W_l row, wf/wg/wo=0.
#define ACCP(M) do { \
    unsigned _lo = (unsigned)__builtin_amdgcn_readlane(hb, 2*(M)); \
    unsigned _hi = (unsigned)__builtin_amdgcn_readlane(hb, 2*(M)+1); \
    unsigned _hp = _lo | (_hi << 16); \
    ai = dot2_(_hp, w##M,  ai); af = dot2_(_hp, wf##M, af); \
    ag = dot2_(_hp, wg##M, ag); ao = dot2_(_hp, wo##M, ao); \
} while(0)

// Blocks: 128 thr = 2 waves = 2 directions. Per wave: lanes 0-39 = LSTM units
// (80 packed-f16 W_hh words in regs, h feedback via readlane), lanes 40-59 =
// logit riders. At iteration s the broadcast h is h_{s-1}, so the rider's
// u = h·W_l belongs to output step s-1 (this was Round 8's off-by-one).
// Triple-buffered u-ring: batch B completes only at iteration B*SS+SS (first
// iter of super-step B+1), so mod-3 buffering gives a safe 2-super-step
// overwrite margin for the store pass. One extra iteration s=SPC finishes
// the last batch. 1024 blocks -> 4 blocks/CU (8 waves/CU) for stall overlap.
extern "C" __global__ void
__attribute__((amdgpu_waves_per_eu(1, 2), amdgpu_flat_work_group_size(NTHR, NTHR)))
bilstm_kernel(const int* __restrict__ tokens,
              const float* __restrict__ embed,
              const float* __restrict__ W_ih1, const float* __restrict__ W_hh1,
              const float* __restrict__ b_ih1, const float* __restrict__ b_hh1,
              const float* __restrict__ W_ih2, const float* __restrict__ W_hh2,
              const float* __restrict__ b_ih2, const float* __restrict__ b_hh2,
              const float* __restrict__ W_l1,  const float* __restrict__ b_l1,
              const float* __restrict__ W_l2,  const float* __restrict__ b_l2,
              float* __restrict__ out)
{
    __shared__ __align__(16) u32x2 xtab[2][NV][NH];        // f16-pair x-pre: (xi,xf),(xg,xo)
    __shared__ __align__(16) float uring[3][2][SS][NV];    // [buf][dir][slot][v]
    __shared__ __align__(16) float embS[NV * NE];
    __shared__ float biasS[NV];
    __shared__ int   tokS[2][SPC];

    const int tid  = threadIdx.x;
    const int wave = tid >> 6;          // == direction
    const int lane = tid & 63;
    const int dir  = wave;
    const int a    = blockIdx.x * CHUNK;

    // ---- stage embed + tokens + bias ----
    for (int p = tid; p < NV * NE; p += NTHR) embS[p] = embed[p];
    for (int p = tid; p < SPC; p += NTHR) {
        int t = a - WARM + p;
        if (t >= 0) {
            tokS[0][p] = tokens[t];
            tokS[1][p] = tokens[T_LEN - 1 - t];
        }
    }
    if (tid < NV) biasS[tid] = b_l1[tid] + b_l2[tid];
    __syncthreads();

    // ---- build x-pre table (f16 pairs): xtab[d][v][k] = {(xi,xf),(xg,xo)} ----
    for (int p = tid; p < 2 * NV * NH; p += NTHR) {
        int k = p % NH, q = p / NH;
        int v = q % NV, dd = q / NV;
        const float* Wih = dd ? W_ih2 : W_ih1;
        const float* bi  = dd ? b_ih2 : b_ih1;
        const float* bh  = dd ? b_hh2 : b_hh1;
        float x[4];
        #pragma unroll
        for (int g = 0; g < 4; ++g) {
            int j = g * NH + k;
            float acc = bi[j] + bh[j];
            #pragma unroll
            for (int e = 0; e < NE; ++e) acc += embS[v * NE + e] * Wih[j * NE + e];
            x[g] = acc;
        }
        u32x2 pk; pk.x = pkf_(x[0], x[1]); pk.y = pkf_(x[2], x[3]);
        xtab[dd][v][k] = pk;
    }

    // ---- per-lane weights in named scalar registers ----
    const bool isUnit  = (lane < NH);
    const bool isLogit = (lane >= NH) && (lane < NH + NV);
    const int  kli     = isUnit ? lane : NH - 1;    // clamped xtab lane index

    D20(w); D20(wf); D20(wg); D20(wo);
    if (isUnit) {
        const float* Whh = dir ? W_hh2 : W_hh1;
        L20(w,  Whh + (0 * NH + lane) * NH);
        L20(wf, Whh + (1 * NH + lane) * NH);
        L20(wg, Whh + (2 * NH + lane) * NH);
        L20(wo, Whh + (3 * NH + lane) * NH);
    } else {
        const float* Wl = dir ? W_l2 : W_l1;
        int vv = isLogit ? (lane - NH) : 0;
        L20(w, Wl + vv * NH);
        Z20(wf); Z20(wg); Z20(wo);
    }
    __syncthreads();   // xtab + tokS ready

    // ---- init + first x prefetch ----
    const int cell_ss0 = (a < WARM) ? WUSS : 0;   // block 0 starts exactly at s=WARM
    int   hb = 0;                                  // f16 bits of own h (lanes 0-39)
    float c  = 0.f;
    u32x2 xv;
    {
        int tk = tokS[dir][cell_ss0 * SS];
        xv = xtab[dir][tk][kli];
    }

    // ---- main loop (super-step NSS = 1 extra iteration to finish last batch) ----
    #pragma unroll 1
    for (int ss = cell_ss0; ss <= NSS; ++ss) {
        const int sbase = ss * SS;
        const int nsl   = (ss < NSS) ? SS : 1;
        #pragma unroll 1
        for (int sl = 0; sl < nsl; ++sl) {
            const int s = sbase + sl;
            K20(w); K20(wf); K20(wg); K20(wo);     // pin weights in VGPRs per iter
            float ai = 0.f, af = 0.f, ag = 0.f, ao = 0.f;
            if (isUnit) {
                ai = lo16f_(xv.x); af = hi16f_(xv.x);
                ag = lo16f_(xv.y); ao = hi16f_(xv.y);
            }
            ACCP(0);  ACCP(1);  ACCP(2);  ACCP(3);  ACCP(4);
            ACCP(5);  ACCP(6);  ACCP(7);  ACCP(8);  ACCP(9);
            ACCP(10); ACCP(11); ACCP(12); ACCP(13); ACCP(14);
            ACCP(15); ACCP(16); ACCP(17); ACCP(18); ACCP(19);
            const float uval = ai;                  // logit lanes: u = h_{s-1}·W_l
            if (isLogit && s >= 1) {                // belongs to output step s-1
                int us = s - 1;
                uring[(us >> 5) % 3][dir][us & 31][lane - NH] = uval;
            }
            int sn = (s + 1 < SPC) ? s + 1 : SPC - 1;
            int tk = tokS[dir][sn];
            xv = xtab[dir][tk][kli];                // prefetch next x
            float I = sig_(ai), F = sig_(af), G = tanh_(ag), O = sig_(ao);
            c = fmaf(F, c, I * G);
            float hh = O * tanh_(c);
            hb = (int)__half_as_ushort(__float2half(hh));
        }
        __syncthreads();
        if (wave == 0 && ss > WUSS) {               // store finished batch B = ss-1
            const int B   = ss - 1;
            const int buf = B % 3;
            const size_t rbase = (size_t)(a + B * SS - WARM) * NV;
            #pragma unroll
            for (int i = 0; i < (SS * NV) / 64; ++i) {   // 10
                int e = i * 64 + lane;
                int row = e / NV, v = e - row * NV;
                float sum = uring[buf][0][row][v] + uring[buf][1][row][v] + biasS[v];
                out[rbase + e] = sum;
            }
        }
    }
}

extern "C" void kernel_launch(void* const* d_in, const int* in_sizes, int n_in,
                              void* d_out, int out_size, void* d_ws, size_t ws_size,
                              hipStream_t stream)
{
    const int*   tokens = (const int*)  d_in[0];
    const float* embed  = (const float*)d_in[1];
    const float* W_ih1  = (const float*)d_in[2];
    const float* W_hh1  = (const float*)d_in[3];
    const float* b_ih1  = (const float*)d_in[4];
    const float* b_hh1  = (const float*)d_in[5];
    const float* W_ih2  = (const float*)d_in[6];
    const float* W_hh2  = (const float*)d_in[7];
    const float* b_ih2  = (const float*)d_in[8];
    const float* b_hh2  = (const float*)d_in[9];
    const float* W_l1   = (const float*)d_in[10];
    const float* b_l1   = (const float*)d_in[11];
    const float* W_l2   = (const float*)d_in[12];
    const float* b_l2   = (const float*)d_in[13];
    float* outp = (float*)d_out;

    hipLaunchKernelGGL(bilstm_kernel, dim3(NBLK), dim3(NTHR), 0, stream,
                       tokens, embed, W_ih1, W_hh1, b_ih1, b_hh1,
                       W_ih2, W_hh2, b_ih2, b_hh2, W_l1, b_l1, W_l2, b_l2, outp);
}

// Round 10
// 347.738 us; speedup vs baseline: 1.7841x; 1.2004x over previous
//
#include <hip/hip_runtime.h>
#include <hip/hip_fp16.h>

#define T_LEN   262144
#define NV      20
#define NE      30
#define NH      40
#define CHUNK   256
#define WARM    64
#define SPC     (WARM + CHUNK)         // 320
#define NBLK    (T_LEN / CHUNK)        // 1024
#define SS      32                     // steps per super-step
#define NSS     (SPC / SS)             // 10
#define WUSS    (WARM / SS)            // 2
#define NTHR    128
#define NW4     1600                   // uint4 count: W_hh packs
#define NW4L    200                    // uint4 count: W_l packs

typedef _Float16 half2v __attribute__((ext_vector_type(2)));
typedef unsigned u32x2  __attribute__((ext_vector_type(2)));

__device__ __forceinline__ float sig_(float x) {
    x = fminf(fmaxf(x, -30.f), 30.f);
    return __fdividef(1.f, 1.f + __expf(-x));
}
__device__ __forceinline__ float tanh_(float x) {
    x = fminf(fmaxf(x, -15.f), 15.f);
    float e = __expf(2.f * x);
    return __fdividef(e - 1.f, e + 1.f);
}
__device__ __forceinline__ unsigned pkf_(float a, float b) {
    unsigned lo = (unsigned)__half_as_ushort(__float2half(a));
    unsigned hi = (unsigned)__half_as_ushort(__float2half(b));
    return lo | (hi << 16);
}
__device__ __forceinline__ float lo16f_(unsigned u) {
    return __half2float(__ushort_as_half((unsigned short)(u & 0xffffu)));
}
__device__ __forceinline__ float hi16f_(unsigned u) {
    return __half2float(__ushort_as_half((unsigned short)(u >> 16)));
}
__device__ __forceinline__ float dot2_(unsigned hp, unsigned wp, float c) {
#if __has_builtin(__builtin_amdgcn_fdot2)
    return __builtin_amdgcn_fdot2(__builtin_bit_cast(half2v, hp),
                                  __builtin_bit_cast(half2v, wp), c, false);
#else
    __half2 h = __builtin_bit_cast(__half2, hp);
    __half2 w = __builtin_bit_cast(__half2, wp);
    return fmaf(__half2float(h.x), __half2float(w.x),
           fmaf(__half2float(h.y), __half2float(w.y), c));
#endif
}
// Opaque 16B load: asm-produced values cannot be rematerialized/re-derived
// by the register allocator -> they must stay in VGPRs (or spill, which
// K20-per-iter makes strictly worse than residency).
__device__ __forceinline__ uint4 gload16_(const uint4* p) {
    uint4 r;
    asm volatile("global_load_dwordx4 %0, %1, off\n\ts_waitcnt vmcnt(0)"
                 : "=v"(r) : "v"(p) : "memory");
    return r;
}

#define D20(V) unsigned V##0,V##1,V##2,V##3,V##4,V##5,V##6,V##7,V##8,V##9, \
    V##10,V##11,V##12,V##13,V##14,V##15,V##16,V##17,V##18,V##19
#define A20(V, C0, C1, C2, C3, C4) do { \
    V##0 =C0.x; V##1 =C0.y; V##2 =C0.z; V##3 =C0.w; \
    V##4 =C1.x; V##5 =C1.y; V##6 =C1.z; V##7 =C1.w; \
    V##8 =C2.x; V##9 =C2.y; V##10=C2.z; V##11=C2.w; \
    V##12=C3.x; V##13=C3.y; V##14=C3.z; V##15=C3.w; \
    V##16=C4.x; V##17=C4.y; V##18=C4.z; V##19=C4.w; } while(0)
#define Z20(V) do { V##0=V##1=V##2=V##3=V##4=V##5=V##6=V##7=V##8=V##9=0u; \
    V##10=V##11=V##12=V##13=V##14=V##15=V##16=V##17=V##18=V##19=0u; } while(0)
#define K20(V) asm volatile("" : \
    "+v"(V##0),"+v"(V##1),"+v"(V##2),"+v"(V##3),"+v"(V##4), \
    "+v"(V##5),"+v"(V##6),"+v"(V##7),"+v"(V##8),"+v"(V##9), \
    "+v"(V##10),"+v"(V##11),"+v"(V##12),"+v"(V##13),"+v"(V##14), \
    "+v"(V##15),"+v"(V##16),"+v"(V##17),"+v"(V##18),"+v"(V##19))

// one readlane per h-PAIR (pre-packed via shfl_xor) feeding 4 dot chains;
// logit lanes (40..59) ride the same instructions with w=W_l row, wf/wg/wo=0.
#define ACCP(M) do { \
    unsigned _hp = (unsigned)__builtin_amdgcn_readlane(hpair, 2*(M)); \
    ai = dot2_(_hp, w##M,  ai); af = dot2_(_hp, wf##M, af); \
    ag = dot2_(_hp, wg##M, ag); ao = dot2_(_hp, wo##M, ao); \
} while(0)

// ---- prep kernel: pack weights as f16 pairs into d_ws ----
// wsW[((dir*4+g)*5+m4)*40+k] = uint4 of pairs m=4*m4+u of W_hh[g*40+k][.]
// wsW[1600 + (dir*5+m4)*20+v] = uint4 of pairs of W_l[v][.]
extern "C" __global__ void prep_kernel(const float* __restrict__ W_hh1,
                                       const float* __restrict__ W_hh2,
                                       const float* __restrict__ W_l1,
                                       const float* __restrict__ W_l2,
                                       uint4* __restrict__ ws)
{
    int tid = blockIdx.x * blockDim.x + threadIdx.x;
    for (int p = tid; p < NW4 + NW4L; p += blockDim.x * gridDim.x) {
        uint4 o;
        if (p < NW4) {
            int k = p % NH, r = p / NH;
            int m4 = r % 5;  r /= 5;
            int g  = r % 4;
            int dd = r / 4;
            const float* W = dd ? W_hh2 : W_hh1;
            const float* row = W + (g * NH + k) * NH + 8 * m4;
            o.x = pkf_(row[0], row[1]); o.y = pkf_(row[2], row[3]);
            o.z = pkf_(row[4], row[5]); o.w = pkf_(row[6], row[7]);
        } else {
            int q = p - NW4;
            int v = q % NV, r = q / NV;
            int m4 = r % 5;
            int dd = r / 5;
            const float* W = dd ? W_l2 : W_l1;
            const float* row = W + v * NH + 8 * m4;
            o.x = pkf_(row[0], row[1]); o.y = pkf_(row[2], row[3]);
            o.z = pkf_(row[4], row[5]); o.w = pkf_(row[6], row[7]);
        }
        ws[p] = o;
    }
}

// Blocks: 128 thr = 2 waves = 2 directions. Per wave: lanes 0-39 = LSTM units
// (80 packed-f16 W_hh words, asm-opaque VGPR-resident), lanes 40-59 = logit
// riders (u = h_{s-1}·W_l on the same broadcasts). Triple-buffered u-ring,
// one barrier / 32 steps; wave 0 stores finished 32-row batches.
// 1024 blocks -> 4 blocks/CU (2 waves/SIMD) for stall overlap.
extern "C" __global__ void
__attribute__((amdgpu_waves_per_eu(1, 2), amdgpu_flat_work_group_size(NTHR, NTHR)))
bilstm_kernel(const int* __restrict__ tokens,
              const float* __restrict__ embed,
              const float* __restrict__ W_ih1,
              const float* __restrict__ b_ih1, const float* __restrict__ b_hh1,
              const float* __restrict__ W_ih2,
              const float* __restrict__ b_ih2, const float* __restrict__ b_hh2,
              const float* __restrict__ b_l1,  const float* __restrict__ b_l2,
              const uint4* __restrict__ wpk,
              float* __restrict__ out)
{
    __shared__ __align__(16) u32x2 xtab[2][NV][NH];        // f16-pair x-pre: (xi,xf),(xg,xo)
    __shared__ __align__(16) float uring[3][2][SS][NV];    // [buf][dir][slot][v]
    __shared__ __align__(16) float embS[NV * NE];
    __shared__ float biasS[NV];
    __shared__ int   tokS[2][SPC];

    const int tid  = threadIdx.x;
    const int wave = tid >> 6;          // == direction
    const int lane = tid & 63;
    const int dir  = wave;
    const int a    = blockIdx.x * CHUNK;

    // ---- stage embed + tokens + bias ----
    for (int p = tid; p < NV * NE; p += NTHR) embS[p] = embed[p];
    for (int p = tid; p < SPC; p += NTHR) {
        int t = a - WARM + p;
        if (t >= 0) {
            tokS[0][p] = tokens[t];
            tokS[1][p] = tokens[T_LEN - 1 - t];
        }
    }
    if (tid < NV) biasS[tid] = b_l1[tid] + b_l2[tid];
    __syncthreads();

    // ---- build x-pre table (f16 pairs): xtab[d][v][k] = {(xi,xf),(xg,xo)} ----
    for (int p = tid; p < 2 * NV * NH; p += NTHR) {
        int k = p % NH, q = p / NH;
        int v = q % NV, dd = q / NV;
        const float* Wih = dd ? W_ih2 : W_ih1;
        const float* bi  = dd ? b_ih2 : b_ih1;
        const float* bh  = dd ? b_hh2 : b_hh1;
        float x[4];
        #pragma unroll
        for (int g = 0; g < 4; ++g) {
            int j = g * NH + k;
            float acc = bi[j] + bh[j];
            #pragma unroll
            for (int e = 0; e < NE; ++e) acc += embS[v * NE + e] * Wih[j * NE + e];
            x[g] = acc;
        }
        u32x2 pk; pk.x = pkf_(x[0], x[1]); pk.y = pkf_(x[2], x[3]);
        xtab[dd][v][k] = pk;
    }

    // ---- per-lane weights: opaque 16B loads of pre-packed words ----
    const bool isUnit  = (lane < NH);
    const bool isLogit = (lane >= NH) && (lane < NH + NV);
    const int  kli     = isUnit ? lane : NH - 1;    // clamped xtab lane index

    D20(w); D20(wf); D20(wg); D20(wo);
    if (isUnit) {
        const uint4* b0 = wpk + ((dir * 4 + 0) * 5) * NH + lane;
        const uint4* b1 = wpk + ((dir * 4 + 1) * 5) * NH + lane;
        const uint4* b2 = wpk + ((dir * 4 + 2) * 5) * NH + lane;
        const uint4* b3 = wpk + ((dir * 4 + 3) * 5) * NH + lane;
        uint4 c0, c1, c2, c3, c4;
        c0=gload16_(b0); c1=gload16_(b0+NH); c2=gload16_(b0+2*NH); c3=gload16_(b0+3*NH); c4=gload16_(b0+4*NH);
        A20(w,  c0, c1, c2, c3, c4);
        c0=gload16_(b1); c1=gload16_(b1+NH); c2=gload16_(b1+2*NH); c3=gload16_(b1+3*NH); c4=gload16_(b1+4*NH);
        A20(wf, c0, c1, c2, c3, c4);
        c0=gload16_(b2); c1=gload16_(b2+NH); c2=gload16_(b2+2*NH); c3=gload16_(b2+3*NH); c4=gload16_(b2+4*NH);
        A20(wg, c0, c1, c2, c3, c4);
        c0=gload16_(b3); c1=gload16_(b3+NH); c2=gload16_(b3+2*NH); c3=gload16_(b3+3*NH); c4=gload16_(b3+4*NH);
        A20(wo, c0, c1, c2, c3, c4);
    } else {
        int vv = isLogit ? (lane - NH) : 0;
        const uint4* bl = wpk + NW4 + (dir * 5) * NV + vv;
        uint4 c0, c1, c2, c3, c4;
        c0=gload16_(bl); c1=gload16_(bl+NV); c2=gload16_(bl+2*NV); c3=gload16_(bl+3*NV); c4=gload16_(bl+4*NV);
        A20(w, c0, c1, c2, c3, c4);
        Z20(wf); Z20(wg); Z20(wo);
    }
    __syncthreads();   // xtab + tokS ready

    // ---- init + first x prefetch ----
    const int cell_ss0 = (a < WARM) ? WUSS : 0;   // block 0 starts exactly at s=WARM
    int   hb = 0;                                  // f16 bits of own h (lanes 0-39)
    float c  = 0.f;
    u32x2 xv;
    {
        int tk = tokS[dir][cell_ss0 * SS];
        xv = xtab[dir][tk][kli];
    }

    // ---- main loop (super-step NSS = 1 extra iteration to finish last batch) ----
    #pragma unroll 1
    for (int ss = cell_ss0; ss <= NSS; ++ss) {
        const int sbase = ss * SS;
        const int nsl   = (ss < NSS) ? SS : 1;
        #pragma unroll 1
        for (int sl = 0; sl < nsl; ++sl) {
            const int s = sbase + sl;
            K20(w); K20(wf); K20(wg); K20(wo);     // pin weights in VGPRs per iter
            // pack h pairs: even lane k holds (h_k, h_{k+1})
            unsigned nb = (unsigned)__shfl_xor(hb, 1, 64);
            unsigned hpair = ((unsigned)hb & 0xffffu) | (nb << 16);
            float ai = 0.f, af = 0.f, ag = 0.f, ao = 0.f;
            if (isUnit) {
                ai = lo16f_(xv.x); af = hi16f_(xv.x);
                ag = lo16f_(xv.y); ao = hi16f_(xv.y);
            }
            ACCP(0);  ACCP(1);  ACCP(2);  ACCP(3);  ACCP(4);
            ACCP(5);  ACCP(6);  ACCP(7);  ACCP(8);  ACCP(9);
            ACCP(10); ACCP(11); ACCP(12); ACCP(13); ACCP(14);
            ACCP(15); ACCP(16); ACCP(17); ACCP(18); ACCP(19);
            const float uval = ai;                  // logit lanes: u = h_{s-1}·W_l
            if (isLogit && s >= 1) {                // belongs to output step s-1
                int us = s - 1;
                uring[(us >> 5) % 3][dir][us & 31][lane - NH] = uval;
            }
            int sn = (s + 1 < SPC) ? s + 1 : SPC - 1;
            int tk = tokS[dir][sn];
            xv = xtab[dir][tk][kli];                // prefetch next x
            float I = sig_(ai), F = sig_(af), G = tanh_(ag), O = sig_(ao);
            c = fmaf(F, c, I * G);
            float hh = O * tanh_(c);
            hb = (int)__half_as_ushort(__float2half(hh));
        }
        __syncthreads();
        if (wave == 0 && ss > WUSS) {               // store finished batch B = ss-1
            const int B   = ss - 1;
            const int buf = B % 3;
            const size_t rbase = (size_t)(a + B * SS - WARM) * NV;
            #pragma unroll
            for (int i = 0; i < (SS * NV) / 64; ++i) {   // 10
                int e = i * 64 + lane;
                int row = e / NV, v = e - row * NV;
                float sum = uring[buf][0][row][v] + uring[buf][1][row][v] + biasS[v];
                out[rbase + e] = sum;
            }
        }
    }
}

extern "C" void kernel_launch(void* const* d_in, const int* in_sizes, int n_in,
                              void* d_out, int out_size, void* d_ws, size_t ws_size,
                              hipStream_t stream)
{
    const int*   tokens = (const int*)  d_in[0];
    const float* embed  = (const float*)d_in[1];
    const float* W_ih1  = (const float*)d_in[2];
    const float* W_hh1  = (const float*)d_in[3];
    const float* b_ih1  = (const float*)d_in[4];
    const float* b_hh1  = (const float*)d_in[5];
    const float* W_ih2  = (const float*)d_in[6];
    const float* W_hh2  = (const float*)d_in[7];
    const float* b_ih2  = (const float*)d_in[8];
    const float* b_hh2  = (const float*)d_in[9];
    const float* W_l1   = (const float*)d_in[10];
    const float* b_l1   = (const float*)d_in[11];
    const float* W_l2   = (const float*)d_in[12];
    const float* b_l2   = (const float*)d_in[13];
    float* outp = (float*)d_out;
    uint4* wpk  = (uint4*)d_ws;

    hipLaunchKernelGGL(prep_kernel, dim3(8), dim3(256), 0, stream,
                       W_hh1, W_hh2, W_l1, W_l2, wpk);
    hipLaunchKernelGGL(bilstm_kernel, dim3(NBLK), dim3(NTHR), 0, stream,
                       tokens, embed, W_ih1, b_ih1, b_hh1,
                       W_ih2, b_ih2, b_hh2, b_l1, b_l2, wpk, outp);
}

// Round 11
// 343.810 us; speedup vs baseline: 1.8045x; 1.0114x over previous
//
#include <hip/hip_runtime.h>
#include <hip/hip_fp16.h>

#define T_LEN   262144
#define NV      20
#define NE      30
#define NH      40
#define CHUNK   256
#define WARM    64
#define SPC     (WARM + CHUNK)         // 320
#define NBLK    (T_LEN / CHUNK)        // 1024
#define SS      32                     // steps per super-step
#define NSS     (SPC / SS)             // 10
#define WUSS    (WARM / SS)            // 2
#define NTHR    128
#define NW4     1600                   // uint4 count: W_hh packs
#define NW4L    200                    // uint4 count: W_l packs

typedef _Float16 half2v __attribute__((ext_vector_type(2)));
typedef unsigned u32x2  __attribute__((ext_vector_type(2)));

__device__ __forceinline__ float sig_(float x) {
    x = fminf(fmaxf(x, -30.f), 30.f);
    return __fdividef(1.f, 1.f + __expf(-x));
}
__device__ __forceinline__ float tanh_(float x) {
    x = fminf(fmaxf(x, -15.f), 15.f);
    float e = __expf(2.f * x);
    return __fdividef(e - 1.f, e + 1.f);
}
__device__ __forceinline__ unsigned pkf_(float a, float b) {
    unsigned lo = (unsigned)__half_as_ushort(__float2half(a));
    unsigned hi = (unsigned)__half_as_ushort(__float2half(b));
    return lo | (hi << 16);
}
__device__ __forceinline__ float lo16f_(unsigned u) {
    return __half2float(__ushort_as_half((unsigned short)(u & 0xffffu)));
}
__device__ __forceinline__ float hi16f_(unsigned u) {
    return __half2float(__ushort_as_half((unsigned short)(u >> 16)));
}
__device__ __forceinline__ float dot2_(unsigned hp, unsigned wp, float c) {
#if __has_builtin(__builtin_amdgcn_fdot2)
    return __builtin_amdgcn_fdot2(__builtin_bit_cast(half2v, hp),
                                  __builtin_bit_cast(half2v, wp), c, false);
#else
    __half2 h = __builtin_bit_cast(__half2, hp);
    __half2 w = __builtin_bit_cast(__half2, wp);
    return fmaf(__half2float(h.x), __half2float(w.x),
           fmaf(__half2float(h.y), __half2float(w.y), c));
#endif
}
// Opaque 16B load: asm-produced values cannot be rematerialized/re-derived
// by the register allocator. They live in the unified VGPR/AGPR file for the
// whole loop; dot2 (VOP3P) can source AGPRs directly, so NO per-iteration
// pinning is needed (R10's per-iter "+v" pin forced 160 accvgpr copies/step).
__device__ __forceinline__ uint4 gload16_(const uint4* p) {
    uint4 r;
    asm volatile("global_load_dwordx4 %0, %1, off\n\ts_waitcnt vmcnt(0)"
                 : "=v"(r) : "v"(p) : "memory");
    return r;
}

#define D20(V) unsigned V##0,V##1,V##2,V##3,V##4,V##5,V##6,V##7,V##8,V##9, \
    V##10,V##11,V##12,V##13,V##14,V##15,V##16,V##17,V##18,V##19
#define A20(V, C0, C1, C2, C3, C4) do { \
    V##0 =C0.x; V##1 =C0.y; V##2 =C0.z; V##3 =C0.w; \
    V##4 =C1.x; V##5 =C1.y; V##6 =C1.z; V##7 =C1.w; \
    V##8 =C2.x; V##9 =C2.y; V##10=C2.z; V##11=C2.w; \
    V##12=C3.x; V##13=C3.y; V##14=C3.z; V##15=C3.w; \
    V##16=C4.x; V##17=C4.y; V##18=C4.z; V##19=C4.w; } while(0)
#define Z20(V) do { V##0=V##1=V##2=V##3=V##4=V##5=V##6=V##7=V##8=V##9=0u; \
    V##10=V##11=V##12=V##13=V##14=V##15=V##16=V##17=V##18=V##19=0u; } while(0)

// one readlane per h-PAIR (pre-packed via shfl_xor) feeding 4 dot chains;
// logit lanes (40..59) ride the same instructions with w=W_l row, wf/wg/wo=0.
#define ACCP(M) do { \
    unsigned _hp = (unsigned)__builtin_amdgcn_readlane(hpair, 2*(M)); \
    ai = dot2_(_hp, w##M,  ai); af = dot2_(_hp, wf##M, af); \
    ag = dot2_(_hp, wg##M, ag); ao = dot2_(_hp, wo##M, ao); \
} while(0)

// ---- prep kernel: pack weights as f16 pairs into d_ws ----
// wsW[((dir*4+g)*5+m4)*40+k] = uint4 of pairs m=4*m4+u of W_hh[g*40+k][.]
// wsW[1600 + (dir*5+m4)*20+v] = uint4 of pairs of W_l[v][.]
extern "C" __global__ void prep_kernel(const float* __restrict__ W_hh1,
                                       const float* __restrict__ W_hh2,
                                       const float* __restrict__ W_l1,
                                       const float* __restrict__ W_l2,
                                       uint4* __restrict__ ws)
{
    int tid = blockIdx.x * blockDim.x + threadIdx.x;
    for (int p = tid; p < NW4 + NW4L; p += blockDim.x * gridDim.x) {
        uint4 o;
        if (p < NW4) {
            int k = p % NH, r = p / NH;
            int m4 = r % 5;  r /= 5;
            int g  = r % 4;
            int dd = r / 4;
            const float* W = dd ? W_hh2 : W_hh1;
            const float* row = W + (g * NH + k) * NH + 8 * m4;
            o.x = pkf_(row[0], row[1]); o.y = pkf_(row[2], row[3]);
            o.z = pkf_(row[4], row[5]); o.w = pkf_(row[6], row[7]);
        } else {
            int q = p - NW4;
            int v = q % NV, r = q / NV;
            int m4 = r % 5;
            int dd = r / 5;
            const float* W = dd ? W_l2 : W_l1;
            const float* row = W + v * NH + 8 * m4;
            o.x = pkf_(row[0], row[1]); o.y = pkf_(row[2], row[3]);
            o.z = pkf_(row[4], row[5]); o.w = pkf_(row[6], row[7]);
        }
        ws[p] = o;
    }
}

// Blocks: 128 thr = 2 waves = 2 directions. Per wave: lanes 0-39 = LSTM units
// (80 packed-f16 W_hh words, asm-opaque register-resident), lanes 40-59 =
// logit riders (u = h_{s-1}·W_l on the same broadcasts). Triple-buffered
// u-ring, one barrier / 32 steps; wave 0 stores finished 32-row batches.
// 1024 blocks -> 4 blocks/CU (2 waves/SIMD) for stall overlap.
extern "C" __global__ void
__attribute__((amdgpu_waves_per_eu(1, 2), amdgpu_flat_work_group_size(NTHR, NTHR)))
bilstm_kernel(const int* __restrict__ tokens,
              const float* __restrict__ embed,
              const float* __restrict__ W_ih1,
              const float* __restrict__ b_ih1, const float* __restrict__ b_hh1,
              const float* __restrict__ W_ih2,
              const float* __restrict__ b_ih2, const float* __restrict__ b_hh2,
              const float* __restrict__ b_l1,  const float* __restrict__ b_l2,
              const uint4* __restrict__ wpk,
              float* __restrict__ out)
{
    __shared__ __align__(16) u32x2 xtab[2][NV][NH];        // f16-pair x-pre: (xi,xf),(xg,xo)
    __shared__ __align__(16) float uring[3][2][SS][NV];    // [buf][dir][slot][v]
    __shared__ __align__(16) float embS[NV * NE];
    __shared__ float biasS[NV];
    __shared__ int   tokS[2][SPC];

    const int tid  = threadIdx.x;
    const int wave = tid >> 6;          // == direction
    const int lane = tid & 63;
    const int dir  = wave;
    const int a    = blockIdx.x * CHUNK;

    // ---- stage embed + tokens + bias ----
    for (int p = tid; p < NV * NE; p += NTHR) embS[p] = embed[p];
    for (int p = tid; p < SPC; p += NTHR) {
        int t = a - WARM + p;
        if (t >= 0) {
            tokS[0][p] = tokens[t];
            tokS[1][p] = tokens[T_LEN - 1 - t];
        }
    }
    if (tid < NV) biasS[tid] = b_l1[tid] + b_l2[tid];
    __syncthreads();

    // ---- build x-pre table (f16 pairs): xtab[d][v][k] = {(xi,xf),(xg,xo)} ----
    for (int p = tid; p < 2 * NV * NH; p += NTHR) {
        int k = p % NH, q = p / NH;
        int v = q % NV, dd = q / NV;
        const float* Wih = dd ? W_ih2 : W_ih1;
        const float* bi  = dd ? b_ih2 : b_ih1;
        const float* bh  = dd ? b_hh2 : b_hh1;
        float x[4];
        #pragma unroll
        for (int g = 0; g < 4; ++g) {
            int j = g * NH + k;
            float acc = bi[j] + bh[j];
            #pragma unroll
            for (int e = 0; e < NE; ++e) acc += embS[v * NE + e] * Wih[j * NE + e];
            x[g] = acc;
        }
        u32x2 pk; pk.x = pkf_(x[0], x[1]); pk.y = pkf_(x[2], x[3]);
        xtab[dd][v][k] = pk;
    }

    // ---- per-lane weights: opaque 16B loads of pre-packed words ----
    const bool isUnit  = (lane < NH);
    const bool isLogit = (lane >= NH) && (lane < NH + NV);
    const int  kli     = isUnit ? lane : NH - 1;    // clamped xtab lane index

    D20(w); D20(wf); D20(wg); D20(wo);
    if (isUnit) {
        const uint4* b0 = wpk + ((dir * 4 + 0) * 5) * NH + lane;
        const uint4* b1 = wpk + ((dir * 4 + 1) * 5) * NH + lane;
        const uint4* b2 = wpk + ((dir * 4 + 2) * 5) * NH + lane;
        const uint4* b3 = wpk + ((dir * 4 + 3) * 5) * NH + lane;
        uint4 c0, c1, c2, c3, c4;
        c0=gload16_(b0); c1=gload16_(b0+NH); c2=gload16_(b0+2*NH); c3=gload16_(b0+3*NH); c4=gload16_(b0+4*NH);
        A20(w,  c0, c1, c2, c3, c4);
        c0=gload16_(b1); c1=gload16_(b1+NH); c2=gload16_(b1+2*NH); c3=gload16_(b1+3*NH); c4=gload16_(b1+4*NH);
        A20(wf, c0, c1, c2, c3, c4);
        c0=gload16_(b2); c1=gload16_(b2+NH); c2=gload16_(b2+2*NH); c3=gload16_(b2+3*NH); c4=gload16_(b2+4*NH);
        A20(wg, c0, c1, c2, c3, c4);
        c0=gload16_(b3); c1=gload16_(b3+NH); c2=gload16_(b3+2*NH); c3=gload16_(b3+3*NH); c4=gload16_(b3+4*NH);
        A20(wo, c0, c1, c2, c3, c4);
    } else {
        int vv = isLogit ? (lane - NH) : 0;
        const uint4* bl = wpk + NW4 + (dir * 5) * NV + vv;
        uint4 c0, c1, c2, c3, c4;
        c0=gload16_(bl); c1=gload16_(bl+NV); c2=gload16_(bl+2*NV); c3=gload16_(bl+3*NV); c4=gload16_(bl+4*NV);
        A20(w, c0, c1, c2, c3, c4);
        Z20(wf); Z20(wg); Z20(wo);
    }
    __syncthreads();   // xtab + tokS ready

    // ---- init + first x prefetch ----
    const int cell_ss0 = (a < WARM) ? WUSS : 0;   // block 0 starts exactly at s=WARM
    int   hb = 0;                                  // f16 bits of own h (lanes 0-39)
    float c  = 0.f;
    u32x2 xv;
    {
        int tk = tokS[dir][cell_ss0 * SS];
        xv = xtab[dir][tk][kli];
    }

    // ---- main loop (super-step NSS = 1 extra iteration to finish last batch) ----
    #pragma unroll 1
    for (int ss = cell_ss0; ss <= NSS; ++ss) {
        const int sbase = ss * SS;
        const int nsl   = (ss < NSS) ? SS : 1;
        #pragma unroll 1
        for (int sl = 0; sl < nsl; ++sl) {
            const int s = sbase + sl;
            // pack h pairs: even lane k holds (h_k, h_{k+1})
            unsigned nb = (unsigned)__shfl_xor(hb, 1, 64);
            unsigned hpair = ((unsigned)hb & 0xffffu) | (nb << 16);
            float ai = 0.f, af = 0.f, ag = 0.f, ao = 0.f;
            if (isUnit) {
                ai = lo16f_(xv.x); af = hi16f_(xv.x);
                ag = lo16f_(xv.y); ao = hi16f_(xv.y);
            }
            ACCP(0);  ACCP(1);  ACCP(2);  ACCP(3);  ACCP(4);
            ACCP(5);  ACCP(6);  ACCP(7);  ACCP(8);  ACCP(9);
            ACCP(10); ACCP(11); ACCP(12); ACCP(13); ACCP(14);
            ACCP(15); ACCP(16); ACCP(17); ACCP(18); ACCP(19);
            const float uval = ai;                  // logit lanes: u = h_{s-1}·W_l
            if (isLogit && s >= 1) {                // belongs to output step s-1
                int us = s - 1;
                uring[(us >> 5) % 3][dir][us & 31][lane - NH] = uval;
            }
            int sn = (s + 1 < SPC) ? s + 1 : SPC - 1;
            int tk = tokS[dir][sn];
            xv = xtab[dir][tk][kli];                // prefetch next x
            float I = sig_(ai), F = sig_(af), G = tanh_(ag), O = sig_(ao);
            c = fmaf(F, c, I * G);
            float hh = O * tanh_(c);
            hb = (int)__half_as_ushort(__float2half(hh));
        }
        __syncthreads();
        if (wave == 0 && ss > WUSS) {               // store finished batch B = ss-1
            const int B   = ss - 1;
            const int buf = B % 3;
            const size_t rbase = (size_t)(a + B * SS - WARM) * NV;
            #pragma unroll
            for (int i = 0; i < (SS * NV) / 64; ++i) {   // 10
                int e = i * 64 + lane;
                int row = e / NV, v = e - row * NV;
                float sum = uring[buf][0][row][v] + uring[buf][1][row][v] + biasS[v];
                out[rbase + e] = sum;
            }
        }
    }
}

extern "C" void kernel_launch(void* const* d_in, const int* in_sizes, int n_in,
                              void* d_out, int out_size, void* d_ws, size_t ws_size,
                              hipStream_t stream)
{
    const int*   tokens = (const int*)  d_in[0];
    const float* embed  = (const float*)d_in[1];
    const float* W_ih1  = (const float*)d_in[2];
    const float* W_hh1  = (const float*)d_in[3];
    const float* b_ih1  = (const float*)d_in[4];
    const float* b_hh1  = (const float*)d_in[5];
    const float* W_ih2  = (const float*)d_in[6];
    const float* W_hh2  = (const float*)d_in[7];
    const float* b_ih2  = (const float*)d_in[8];
    const float* b_hh2  = (const float*)d_in[9];
    const float* W_l1   = (const float*)d_in[10];
    const float* b_l1   = (const float*)d_in[11];
    const float* W_l2   = (const float*)d_in[12];
    const float* b_l2   = (const float*)d_in[13];
    float* outp = (float*)d_out;
    uint4* wpk  = (uint4*)d_ws;

    hipLaunchKernelGGL(prep_kernel, dim3(8), dim3(256), 0, stream,
                       W_hh1, W_hh2, W_l1, W_l2, wpk);
    hipLaunchKernelGGL(bilstm_kernel, dim3(NBLK), dim3(NTHR), 0, stream,
                       tokens, embed, W_ih1, b_ih1, b_hh1,
                       W_ih2, b_ih2, b_hh2, b_l1, b_l2, wpk, outp);
}